// Round 3
// baseline (826.605 us; speedup 1.0000x reference)
//
#include <hip/hip_runtime.h>
#include <hip/hip_bf16.h>
#include <stdint.h>

typedef __attribute__((ext_vector_type(8))) short bf16x8;
typedef __attribute__((ext_vector_type(4))) float floatx4;

__device__ __forceinline__ float2 bf2f(uint32_t u) {
  float2 r;
  r.x = __uint_as_float(u << 16);
  r.y = __uint_as_float(u & 0xffff0000u);
  return r;
}
__device__ __forceinline__ uint16_t f2bf(float f) {
  uint32_t u = __float_as_uint(f);
  uint32_t r = (u + 0x7fffu + ((u >> 16) & 1u)) >> 16;
  return (uint16_t)r;
}
__device__ __forceinline__ uint32_t f2bf_pack(float a, float b) {
  return (uint32_t)f2bf(a) | ((uint32_t)f2bf(b) << 16);
}
__device__ __forceinline__ int iclamp(int v, int lo, int hi) {
  return v < lo ? lo : (v > hi ? hi : v);
}

// ---------------- dtype detect: f32 words have exp field ~[90,160] ----------
__global__ void detect_k(const uint32_t* __restrict__ w, int* __restrict__ flag) {
  __shared__ int cnt;
  if (threadIdx.x == 0) cnt = 0;
  __syncthreads();
  uint32_t v = w[threadIdx.x];  // first 256 words of Ws1 (>=1KB in both dtypes)
  int e = (v >> 23) & 0xFF;
  if (e >= 90 && e <= 160) atomicAdd(&cnt, 1);
  __syncthreads();
  if (threadIdx.x == 0) *flag = (cnt >= 128) ? 1 : 0;  // 1 = f32, 0 = bf16
}

// ---------------- transpose+convert 128x128 weight -> bf16 ------------------
__global__ void transp_k(const void* __restrict__ W, __hip_bfloat16* __restrict__ WT,
                         const int* __restrict__ flag) {
  int i = blockIdx.x * 256 + threadIdx.x;  // 16384 total
  int k = i >> 7, n = i & 127;
  uint16_t h;
  if (*flag)
    h = f2bf(((const float*)W)[i]);
  else
    h = ((const uint16_t*)W)[i];
  ((uint16_t*)WT)[n * 128 + k] = h;
}

// ---------------- [M,128] @ [128,128] via MFMA bf16 -------------------------
// A is raw (dtype per flag) at element offset aoff; WT bf16; out bf16 (ws).
__global__ __launch_bounds__(256) void mm_xw(const void* __restrict__ Abase, size_t aoff,
                                             const __hip_bfloat16* __restrict__ WT,
                                             __hip_bfloat16* __restrict__ out, int M,
                                             const int* __restrict__ flag) {
  __shared__ __align__(16) __hip_bfloat16 w[128 * 136];
  int isf32 = *flag;
  int tid = threadIdx.x;
  for (int i = tid; i < 2048; i += 256) {
    int row = i >> 4, ch = i & 15;
    *(uint4*)&w[row * 136 + ch * 8] = *(const uint4*)&WT[row * 128 + ch * 8];
  }
  __syncthreads();
  int wave = tid >> 6, lane = tid & 63;
  int l15 = lane & 15, kq = (lane >> 4) * 8;
  int row0 = blockIdx.x * 64 + wave * 16;
  int m = row0 + l15;
  int mc = m < M ? m : M - 1;
  floatx4 acc[8];
#pragma unroll
  for (int t = 0; t < 8; t++) acc[t] = (floatx4){0.f, 0.f, 0.f, 0.f};
#pragma unroll
  for (int k0 = 0; k0 < 128; k0 += 32) {
    union { bf16x8 v; uint32_t u[4]; } au;
    size_t eoff = aoff + (size_t)mc * 128 + k0 + kq;
    if (isf32) {
      const float* Af = (const float*)Abase + eoff;
      float4 f0 = *(const float4*)Af;
      float4 f1 = *(const float4*)(Af + 4);
      au.u[0] = f2bf_pack(f0.x, f0.y);
      au.u[1] = f2bf_pack(f0.z, f0.w);
      au.u[2] = f2bf_pack(f1.x, f1.y);
      au.u[3] = f2bf_pack(f1.z, f1.w);
    } else {
      au.v = *(const bf16x8*)((const __hip_bfloat16*)Abase + eoff);
    }
#pragma unroll
    for (int t = 0; t < 8; t++) {
      bf16x8 b = *(const bf16x8*)&w[(t * 16 + l15) * 136 + k0 + kq];
      acc[t] = __builtin_amdgcn_mfma_f32_16x16x32_bf16(au.v, b, acc[t], 0, 0, 0);
    }
  }
  int rbase = row0 + (lane >> 4) * 4;
  uint16_t* o16 = (uint16_t*)out;
#pragma unroll
  for (int r = 0; r < 4; r++) {
    int rr = rbase + r;
    if (rr < M) {
#pragma unroll
      for (int t = 0; t < 8; t++) o16[(size_t)rr * 128 + t * 16 + l15] = f2bf(acc[t][r]);
    }
  }
}

// ---------------- es[m,h] = sum_c h[m,h*32+c]*a[h,c]; h bf16, a raw ---------
__global__ void alpha_dot(const __hip_bfloat16* __restrict__ h, const void* __restrict__ a,
                          float* __restrict__ e, int M, const int* __restrict__ flag) {
  int idx = blockIdx.x * 256 + threadIdx.x;
  if (idx >= M * 4) return;
  int isf32 = *flag;
  int m = idx >> 2, hh = idx & 3;
  const uint32_t* hp = (const uint32_t*)(h + (size_t)m * 128 + hh * 32);
  float s = 0.f;
  if (isf32) {
    const float2* ap = (const float2*)((const float*)a + hh * 32);
#pragma unroll
    for (int i = 0; i < 16; i++) {
      float2 hv = bf2f(hp[i]);
      float2 av = ap[i];
      s += hv.x * av.x + hv.y * av.y;
    }
  } else {
    const uint32_t* ap = (const uint32_t*)((const __hip_bfloat16*)a + hh * 32);
#pragma unroll
    for (int i = 0; i < 16; i++) {
      float2 hv = bf2f(hp[i]);
      float2 av = bf2f(ap[i]);
      s += hv.x * av.x + hv.y * av.y;
    }
  }
  e[idx] = s;
}

// ---------------- counting sort helpers ----------------
__global__ void zero_i32(int* p, int n) {
  int i = blockIdx.x * 256 + threadIdx.x;
  if (i < n) p[i] = 0;
}
__global__ void hist_k(const int* __restrict__ dst, int* __restrict__ cnt, int E, int N) {
  int i = blockIdx.x * 256 + threadIdx.x;
  if (i < E) atomicAdd(&cnt[iclamp(dst[i], 0, N - 1)], 1);
}
__global__ void scan_partial(const int* __restrict__ in, int* __restrict__ out,
                             int* __restrict__ bsum, int n) {
  __shared__ int lds[256];
  int t = threadIdx.x;
  int base = blockIdx.x * 1024 + t * 4;
  int v[4];
  int s = 0;
#pragma unroll
  for (int j = 0; j < 4; j++) {
    v[j] = (base + j < n) ? in[base + j] : 0;
    s += v[j];
  }
  lds[t] = s;
  __syncthreads();
  for (int d = 1; d < 256; d <<= 1) {
    int x = 0;
    if (t >= d) x = lds[t - d];
    __syncthreads();
    if (t >= d) lds[t] += x;
    __syncthreads();
  }
  int run = (t > 0) ? lds[t - 1] : 0;
  if (t == 255) bsum[blockIdx.x] = lds[255];
#pragma unroll
  for (int j = 0; j < 4; j++) {
    if (base + j < n) out[base + j] = run;
    run += v[j];
  }
}
__global__ void scan_small(int* bsum, int nb) {
  if (threadIdx.x == 0 && blockIdx.x == 0) {
    int acc = 0;
    for (int i = 0; i < nb; i++) {
      int v = bsum[i];
      bsum[i] = acc;
      acc += v;
    }
  }
}
__global__ void scan_add(int* out, const int* bsum, int n) {
  int i = blockIdx.x * 256 + threadIdx.x;
  if (i < n) out[i] += bsum[i >> 10];
}
__global__ void fill_k(const int* __restrict__ src, const int* __restrict__ dst,
                       const int* __restrict__ off, int* __restrict__ cur,
                       int* __restrict__ sorted, int E, int N) {
  int i = blockIdx.x * 256 + threadIdx.x;
  if (i < E) {
    int d = iclamp(dst[i], 0, N - 1);
    int p = off[d] + atomicAdd(&cur[d], 1);
    sorted[iclamp(p, 0, E - 1)] = src[i];
  }
}
__global__ void dinv_k(const int* __restrict__ cnt, float* __restrict__ dinv, int n) {
  int i = blockIdx.x * 256 + threadIdx.x;
  if (i < n) dinv[i] = rsqrtf((float)max(cnt[i], 0) + 1.0f);
}

// ---------------- GAT aggregation: one wave per dst node --------------------
__global__ void gat_agg(const int* __restrict__ off, const int* __restrict__ cnt,
                        const int* __restrict__ ssrc,
                        const __hip_bfloat16* __restrict__ hs,
                        const float* __restrict__ es, const float* __restrict__ ed,
                        const void* __restrict__ xdst, const void* __restrict__ bias,
                        void* __restrict__ outb, size_t ooff,
                        int N, int Ns, int E, const int* __restrict__ flag) {
  int wid = (blockIdx.x * 256 + threadIdx.x) >> 6;
  if (wid >= N) return;
  int isf32 = *flag;
  int lane = threadIdx.x & 63;
  int hh = lane >> 4;
  int c0 = hh * 32 + (lane & 15) * 2;
  int deg = iclamp(cnt[wid], 0, E);
  int o = iclamp(off[wid], 0, E - deg);
  float edv = ed[wid * 4 + hh];
  float mx = -1e30f;
  for (int e = 0; e < deg; e++) {
    int s = iclamp(ssrc[o + e], 0, Ns - 1);
    float ev = es[s * 4 + hh] + edv;
    ev = ev >= 0.f ? ev : 0.2f * ev;
    mx = fmaxf(mx, ev);
  }
  float sum = 0.f, a0 = 0.f, a1 = 0.f;
  for (int e = 0; e < deg; e++) {
    int s = iclamp(ssrc[o + e], 0, Ns - 1);
    float ev = es[s * 4 + hh] + edv;
    ev = ev >= 0.f ? ev : 0.2f * ev;
    float wgt = __expf(ev - mx);
    sum += wgt;
    float2 f = bf2f(*(const uint32_t*)&hs[(size_t)s * 128 + c0]);
    a0 += wgt * f.x;
    a1 += wgt * f.y;
  }
  float inv = 1.f / (sum + 1e-16f);
  float x0, x1, b0, b1;
  if (isf32) {
    const float* xf = (const float*)xdst + (size_t)wid * 128 + c0;
    x0 = xf[0]; x1 = xf[1];
    const float* bf_ = (const float*)bias + c0;
    b0 = bf_[0]; b1 = bf_[1];
  } else {
    float2 xf = bf2f(*(const uint32_t*)&((const __hip_bfloat16*)xdst)[(size_t)wid * 128 + c0]);
    float2 bv = bf2f(*(const uint32_t*)&((const __hip_bfloat16*)bias)[c0]);
    x0 = xf.x; x1 = xf.y; b0 = bv.x; b1 = bv.y;
  }
  float r0 = x0 + 0.5f * (a0 * inv + b0);
  float r1 = x1 + 0.5f * (a1 * inv + b1);
  if (isf32) {
    float* op = (float*)outb + ooff + (size_t)wid * 128 + c0;
    op[0] = r0; op[1] = r1;
  } else {
    *(uint32_t*)&((uint16_t*)outb)[ooff + (size_t)wid * 128 + c0] = f2bf_pack(r0, r1);
  }
}

// ---------------- GCN aggregation: one wave per dst node --------------------
__global__ void gcn_agg(const int* __restrict__ off, const int* __restrict__ cnt,
                        const int* __restrict__ ssrc,
                        const __hip_bfloat16* __restrict__ xw,
                        const float* __restrict__ dinv,
                        const void* __restrict__ x, const void* __restrict__ bias,
                        void* __restrict__ outb, size_t ooff,
                        int N, int E, const int* __restrict__ flag) {
  int wid = (blockIdx.x * 256 + threadIdx.x) >> 6;
  if (wid >= N) return;
  int isf32 = *flag;
  int lane = threadIdx.x & 63;
  int c0 = lane * 2;
  int deg = iclamp(cnt[wid], 0, E);
  int o = iclamp(off[wid], 0, E - deg);
  float a0 = 0.f, a1 = 0.f;
  for (int e = 0; e < deg; e++) {
    int s = iclamp(ssrc[o + e], 0, N - 1);
    float ds = dinv[s];
    float2 f = bf2f(*(const uint32_t*)&xw[(size_t)s * 128 + c0]);
    a0 += ds * f.x;
    a1 += ds * f.y;
  }
  float di = dinv[wid];
  float2 sf = bf2f(*(const uint32_t*)&xw[(size_t)wid * 128 + c0]);
  float agg0 = di * a0 + sf.x * di * di;
  float agg1 = di * a1 + sf.y * di * di;
  float x0, x1, b0, b1;
  if (isf32) {
    const float* xf = (const float*)x + (size_t)wid * 128 + c0;
    x0 = xf[0]; x1 = xf[1];
    const float* bf_ = (const float*)bias + c0;
    b0 = bf_[0]; b1 = bf_[1];
  } else {
    float2 xf = bf2f(*(const uint32_t*)&((const __hip_bfloat16*)x)[(size_t)wid * 128 + c0]);
    float2 bv = bf2f(*(const uint32_t*)&((const __hip_bfloat16*)bias)[c0]);
    x0 = xf.x; x1 = xf.y; b0 = bv.x; b1 = bv.y;
  }
  float r0 = x0 + 0.2f * (agg0 + b0);
  float r1 = x1 + 0.2f * (agg1 + b1);
  if (isf32) {
    float* op = (float*)outb + ooff + (size_t)wid * 128 + c0;
    op[0] = r0; op[1] = r1;
  } else {
    *(uint32_t*)&((uint16_t*)outb)[ooff + (size_t)wid * 128 + c0] = f2bf_pack(r0, r1);
  }
}

extern "C" void kernel_launch(void* const* d_in, const int* in_sizes, int n_in,
                              void* d_out, int out_size, void* d_ws, size_t ws_size,
                              hipStream_t stream) {
  const void* xb = d_in[0];
  const void* xc = d_in[1];
  const void* xt = d_in[2];
  const void* Ws1 = d_in[3];
  const void* Wd1 = d_in[4];
  const void* a_s1 = d_in[5];
  const void* a_d1 = d_in[6];
  const void* b1 = d_in[7];
  const void* Ws2 = d_in[8];
  const void* Wd2 = d_in[9];
  const void* a_s2 = d_in[10];
  const void* a_d2 = d_in[11];
  const void* b2 = d_in[12];
  const void* Wg = d_in[13];
  const void* bg = d_in[14];
  const int* b2c_src = (const int*)d_in[15];
  const int* b2c_dst = (const int*)d_in[16];
  const int* c2t_src = (const int*)d_in[17];
  const int* c2t_dst = (const int*)d_in[18];
  const int* adj_src = (const int*)d_in[19];
  const int* adj_dst = (const int*)d_in[20];

  const int Nb = in_sizes[0] / 128, Nc = in_sizes[1] / 128, Nt = in_sizes[2] / 128;
  const int Ebc = in_sizes[15], Ect = in_sizes[17], Eadj = in_sizes[19];

  auto al = [](size_t x) { return (x + 255) & ~(size_t)255; };
  char* base = (char*)d_ws;

  size_t oFlag = 0;
  size_t oWT = 256;
  size_t oXW = oWT + al(5 * 16384 * 2);       // hs1, later GCN xw (bf16, Nb*256 B)
  size_t oPool = oXW + al((size_t)Nb * 256);  // per-phase scratch pool

  // phase 1 pool
  size_t p1 = oPool;
  size_t o_ed1 = p1; p1 += al((size_t)Nc * 16);
  size_t o_hd1 = p1;
  size_t ov = o_hd1;
  size_t o_es1 = ov; ov += al((size_t)Nb * 16);
  size_t o_cntc = ov; ov += al((size_t)Nc * 4);
  size_t o_offc = ov; ov += al((size_t)Nc * 4);
  size_t o_curc = ov; ov += al((size_t)Nc * 4);
  size_t o_srtbc = ov; ov += al((size_t)Ebc * 4);
  size_t o_bs1 = ov; ov += al(1024);
  size_t slot1 = al((size_t)Nc * 256);
  size_t end1 = o_hd1 + (ov - o_hd1 > slot1 ? ov - o_hd1 : slot1);

  // phase 2 pool
  size_t p2 = oPool;
  size_t o_hs2 = p2; p2 += al((size_t)Nc * 256);
  size_t o_hd2 = p2; p2 += al((size_t)Nt * 256);
  size_t o_es2 = p2; p2 += al((size_t)Nc * 16);
  size_t o_ed2 = p2; p2 += al((size_t)Nt * 16);
  size_t o_cntt = p2; p2 += al((size_t)Nt * 4);
  size_t o_offt = p2; p2 += al((size_t)Nt * 4);
  size_t o_curt = p2; p2 += al((size_t)Nt * 4);
  size_t o_srtct = p2; p2 += al((size_t)Ect * 4);
  size_t o_bs2 = p2; p2 += al(1024);
  size_t end2 = p2;

  // phase 3 pool
  size_t p3 = oPool;
  size_t o_cntb = p3; p3 += al((size_t)Nb * 4);
  size_t o_offb = p3; p3 += al((size_t)Nb * 4);
  size_t o_curb = p3; p3 += al((size_t)Nb * 4);
  size_t o_dinv = p3; p3 += al((size_t)Nb * 4);
  size_t o_srtadj = p3; p3 += al((size_t)Eadj * 4);
  size_t o_bs3 = p3; p3 += al(1024);
  size_t end3 = p3;

  size_t required = end1;
  if (end2 > required) required = end2;
  if (end3 > required) required = end3;
  if (required > ws_size) return;  // diagnostic bail (finite absmax signature)

  int* flag = (int*)(base + oFlag);
  __hip_bfloat16* WT = (__hip_bfloat16*)(base + oWT);
  __hip_bfloat16* XW = (__hip_bfloat16*)(base + oXW);

  const size_t off_b_out = 0;
  const size_t off_c_out = (size_t)Nb * 128;
  const size_t off_t_out = off_c_out + (size_t)Nc * 128;

  detect_k<<<1, 256, 0, stream>>>((const uint32_t*)Ws1, flag);

  transp_k<<<64, 256, 0, stream>>>(Ws1, WT + 0 * 16384, flag);
  transp_k<<<64, 256, 0, stream>>>(Wd1, WT + 1 * 16384, flag);
  transp_k<<<64, 256, 0, stream>>>(Ws2, WT + 2 * 16384, flag);
  transp_k<<<64, 256, 0, stream>>>(Wd2, WT + 3 * 16384, flag);
  transp_k<<<64, 256, 0, stream>>>(Wg, WT + 4 * 16384, flag);

  // ================= Phase 1: GAT building -> cable =================
  {
    __hip_bfloat16* hd1 = (__hip_bfloat16*)(base + o_hd1);
    float* ed1 = (float*)(base + o_ed1);
    mm_xw<<<(Nc + 63) / 64, 256, 0, stream>>>(xc, 0, WT + 1 * 16384, hd1, Nc, flag);
    alpha_dot<<<(Nc * 4 + 255) / 256, 256, 0, stream>>>(hd1, a_d1, ed1, Nc, flag);
    float* es1 = (float*)(base + o_es1);
    int* cnt_c = (int*)(base + o_cntc);
    int* off_c = (int*)(base + o_offc);
    int* cur_c = (int*)(base + o_curc);
    int* srt = (int*)(base + o_srtbc);
    int* bsum = (int*)(base + o_bs1);
    mm_xw<<<(Nb + 63) / 64, 256, 0, stream>>>(xb, 0, WT + 0 * 16384, XW, Nb, flag);
    alpha_dot<<<(Nb * 4 + 255) / 256, 256, 0, stream>>>(XW, a_s1, es1, Nb, flag);
    zero_i32<<<(Nc + 255) / 256, 256, 0, stream>>>(cnt_c, Nc);
    zero_i32<<<(Nc + 255) / 256, 256, 0, stream>>>(cur_c, Nc);
    hist_k<<<(Ebc + 255) / 256, 256, 0, stream>>>(b2c_dst, cnt_c, Ebc, Nc);
    int nblk = (Nc + 1023) / 1024;
    scan_partial<<<nblk, 256, 0, stream>>>(cnt_c, off_c, bsum, Nc);
    scan_small<<<1, 64, 0, stream>>>(bsum, nblk);
    scan_add<<<(Nc + 255) / 256, 256, 0, stream>>>(off_c, bsum, Nc);
    fill_k<<<(Ebc + 255) / 256, 256, 0, stream>>>(b2c_src, b2c_dst, off_c, cur_c, srt, Ebc, Nc);
    gat_agg<<<(int)(((size_t)Nc * 64 + 255) / 256), 256, 0, stream>>>(
        off_c, cnt_c, srt, XW, es1, ed1, xc, b1, d_out, off_c_out, Nc, Nb, Ebc, flag);
  }

  // ================= Phase 2: GAT cable(updated) -> transformer =================
  {
    __hip_bfloat16* hs2 = (__hip_bfloat16*)(base + o_hs2);
    __hip_bfloat16* hd2 = (__hip_bfloat16*)(base + o_hd2);
    float* es2 = (float*)(base + o_es2);
    float* ed2 = (float*)(base + o_ed2);
    int* cnt_t = (int*)(base + o_cntt);
    int* off_t = (int*)(base + o_offt);
    int* cur_t = (int*)(base + o_curt);
    int* srt = (int*)(base + o_srtct);
    int* bsum = (int*)(base + o_bs2);
    mm_xw<<<(Nc + 63) / 64, 256, 0, stream>>>(d_out, off_c_out, WT + 2 * 16384, hs2, Nc, flag);
    mm_xw<<<(Nt + 63) / 64, 256, 0, stream>>>(xt, 0, WT + 3 * 16384, hd2, Nt, flag);
    alpha_dot<<<(Nc * 4 + 255) / 256, 256, 0, stream>>>(hs2, a_s2, es2, Nc, flag);
    alpha_dot<<<(Nt * 4 + 255) / 256, 256, 0, stream>>>(hd2, a_d2, ed2, Nt, flag);
    zero_i32<<<(Nt + 255) / 256, 256, 0, stream>>>(cnt_t, Nt);
    zero_i32<<<(Nt + 255) / 256, 256, 0, stream>>>(cur_t, Nt);
    hist_k<<<(Ect + 255) / 256, 256, 0, stream>>>(c2t_dst, cnt_t, Ect, Nt);
    int nblk = (Nt + 1023) / 1024;
    scan_partial<<<nblk, 256, 0, stream>>>(cnt_t, off_t, bsum, Nt);
    scan_small<<<1, 64, 0, stream>>>(bsum, nblk);
    scan_add<<<(Nt + 255) / 256, 256, 0, stream>>>(off_t, bsum, Nt);
    fill_k<<<(Ect + 255) / 256, 256, 0, stream>>>(c2t_src, c2t_dst, off_t, cur_t, srt, Ect, Nt);
    gat_agg<<<(int)(((size_t)Nt * 64 + 255) / 256), 256, 0, stream>>>(
        off_t, cnt_t, srt, hs2, es2, ed2, xt, b2, d_out, off_t_out, Nt, Nc, Ect, flag);
  }

  // ================= Phase 3: GCN building adjacency =================
  {
    int* cnt_b = (int*)(base + o_cntb);
    int* off_b = (int*)(base + o_offb);
    int* cur_b = (int*)(base + o_curb);
    float* dinv = (float*)(base + o_dinv);
    int* srt = (int*)(base + o_srtadj);
    int* bsum = (int*)(base + o_bs3);
    mm_xw<<<(Nb + 63) / 64, 256, 0, stream>>>(xb, 0, WT + 4 * 16384, XW, Nb, flag);
    zero_i32<<<(Nb + 255) / 256, 256, 0, stream>>>(cnt_b, Nb);
    zero_i32<<<(Nb + 255) / 256, 256, 0, stream>>>(cur_b, Nb);
    hist_k<<<(Eadj + 255) / 256, 256, 0, stream>>>(adj_dst, cnt_b, Eadj, Nb);
    int nblk = (Nb + 1023) / 1024;
    scan_partial<<<nblk, 256, 0, stream>>>(cnt_b, off_b, bsum, Nb);
    scan_small<<<1, 64, 0, stream>>>(bsum, nblk);
    scan_add<<<(Nb + 255) / 256, 256, 0, stream>>>(off_b, bsum, Nb);
    dinv_k<<<(Nb + 255) / 256, 256, 0, stream>>>(cnt_b, dinv, Nb);
    fill_k<<<(Eadj + 255) / 256, 256, 0, stream>>>(adj_src, adj_dst, off_b, cur_b, srt, Eadj, Nb);
    gcn_agg<<<(int)(((size_t)Nb * 64 + 255) / 256), 256, 0, stream>>>(
        off_b, cnt_b, srt, XW, dinv, xb, bg, d_out, off_b_out, Nb, Eadj, flag);
  }
}

// Round 5
// 715.692 us; speedup vs baseline: 1.1550x; 1.1550x over previous
//
#include <hip/hip_runtime.h>
#include <hip/hip_bf16.h>
#include <stdint.h>

typedef __attribute__((ext_vector_type(8))) short bf16x8;
typedef __attribute__((ext_vector_type(4))) float floatx4;
typedef __attribute__((ext_vector_type(4))) float f32x4;
typedef __attribute__((ext_vector_type(2))) float f32x2;

__device__ __forceinline__ float2 bf2f(uint32_t u) {
  float2 r;
  r.x = __uint_as_float(u << 16);
  r.y = __uint_as_float(u & 0xffff0000u);
  return r;
}
__device__ __forceinline__ uint16_t f2bf(float f) {
  uint32_t u = __float_as_uint(f);
  uint32_t r = (u + 0x7fffu + ((u >> 16) & 1u)) >> 16;
  return (uint16_t)r;
}
__device__ __forceinline__ uint32_t f2bf_pack(float a, float b) {
  return (uint32_t)f2bf(a) | ((uint32_t)f2bf(b) << 16);
}
__device__ __forceinline__ int iclamp(int v, int lo, int hi) {
  return v < lo ? lo : (v > hi ? hi : v);
}
__device__ __forceinline__ float lrelu(float v) { return v >= 0.f ? v : 0.2f * v; }

// ---------------- dtype detect: f32 words have exp field ~[90,160] ----------
__global__ void detect_k(const uint32_t* __restrict__ w, int* __restrict__ flag) {
  __shared__ int cnt;
  if (threadIdx.x == 0) cnt = 0;
  __syncthreads();
  uint32_t v = w[threadIdx.x];
  int e = (v >> 23) & 0xFF;
  if (e >= 90 && e <= 160) atomicAdd(&cnt, 1);
  __syncthreads();
  if (threadIdx.x == 0) *flag = (cnt >= 128) ? 1 : 0;  // 1 = f32, 0 = bf16
}

// ---------------- transpose+convert 128x128 weight -> bf16 ------------------
__global__ void transp_k(const void* __restrict__ W, __hip_bfloat16* __restrict__ WT,
                         const int* __restrict__ flag) {
  int i = blockIdx.x * 256 + threadIdx.x;
  int k = i >> 7, n = i & 127;
  uint16_t h;
  if (*flag)
    h = f2bf(((const float*)W)[i]);
  else
    h = ((const uint16_t*)W)[i];
  ((uint16_t*)WT)[n * 128 + k] = h;
}

// ---------------- [M,128] @ [128,128] via MFMA bf16 -------------------------
__global__ __launch_bounds__(256) void mm_xw(const void* __restrict__ Abase, size_t aoff,
                                             const __hip_bfloat16* __restrict__ WT,
                                             __hip_bfloat16* __restrict__ out, int M,
                                             const int* __restrict__ flag) {
  __shared__ __align__(16) __hip_bfloat16 w[128 * 136];
  int isf32 = *flag;
  int tid = threadIdx.x;
  for (int i = tid; i < 2048; i += 256) {
    int row = i >> 4, ch = i & 15;
    *(uint4*)&w[row * 136 + ch * 8] = *(const uint4*)&WT[row * 128 + ch * 8];
  }
  __syncthreads();
  int wave = tid >> 6, lane = tid & 63;
  int l15 = lane & 15, kq = (lane >> 4) * 8;
  int row0 = blockIdx.x * 64 + wave * 16;
  int m = row0 + l15;
  int mc = m < M ? m : M - 1;
  floatx4 acc[8];
#pragma unroll
  for (int t = 0; t < 8; t++) acc[t] = (floatx4){0.f, 0.f, 0.f, 0.f};
#pragma unroll
  for (int k0 = 0; k0 < 128; k0 += 32) {
    union { bf16x8 v; uint32_t u[4]; } au;
    size_t eoff = aoff + (size_t)mc * 128 + k0 + kq;
    if (isf32) {
      const f32x4* Af = (const f32x4*)((const float*)Abase + eoff);
      f32x4 f0 = __builtin_nontemporal_load(Af);
      f32x4 f1 = __builtin_nontemporal_load(Af + 1);
      au.u[0] = f2bf_pack(f0.x, f0.y);
      au.u[1] = f2bf_pack(f0.z, f0.w);
      au.u[2] = f2bf_pack(f1.x, f1.y);
      au.u[3] = f2bf_pack(f1.z, f1.w);
    } else {
      au.v = __builtin_nontemporal_load((const bf16x8*)((const __hip_bfloat16*)Abase + eoff));
    }
#pragma unroll
    for (int t = 0; t < 8; t++) {
      bf16x8 b = *(const bf16x8*)&w[(t * 16 + l15) * 136 + k0 + kq];
      acc[t] = __builtin_amdgcn_mfma_f32_16x16x32_bf16(au.v, b, acc[t], 0, 0, 0);
    }
  }
  int rbase = row0 + (lane >> 4) * 4;
  uint16_t* o16 = (uint16_t*)out;
#pragma unroll
  for (int r = 0; r < 4; r++) {
    int rr = rbase + r;
    if (rr < M) {
#pragma unroll
      for (int t = 0; t < 8; t++) o16[(size_t)rr * 128 + t * 16 + l15] = f2bf(acc[t][r]);
    }
  }
}

// ---------------- es[m,h] = sum_c h[m,h*32+c]*a[h,c] ------------------------
__global__ void alpha_dot(const __hip_bfloat16* __restrict__ h, const void* __restrict__ a,
                          float* __restrict__ e, int M, const int* __restrict__ flag) {
  int idx = blockIdx.x * 256 + threadIdx.x;
  if (idx >= M * 4) return;
  int isf32 = *flag;
  int m = idx >> 2, hh = idx & 3;
  const uint32_t* hp = (const uint32_t*)(h + (size_t)m * 128 + hh * 32);
  float s = 0.f;
  if (isf32) {
    const float2* ap = (const float2*)((const float*)a + hh * 32);
#pragma unroll
    for (int i = 0; i < 16; i++) {
      float2 hv = bf2f(hp[i]);
      float2 av = ap[i];
      s += hv.x * av.x + hv.y * av.y;
    }
  } else {
    const uint32_t* ap = (const uint32_t*)((const __hip_bfloat16*)a + hh * 32);
#pragma unroll
    for (int i = 0; i < 16; i++) {
      float2 hv = bf2f(hp[i]);
      float2 av = bf2f(ap[i]);
      s += hv.x * av.x + hv.y * av.y;
    }
  }
  e[idx] = s;
}

// ---------------- counting sort helpers ----------------
__global__ void zero2_i32(int* p, int* q, int n) {
  int i = blockIdx.x * 256 + threadIdx.x;
  if (i < n) { p[i] = 0; q[i] = 0; }
}
__global__ void hist_k(const int* __restrict__ dst, int* __restrict__ cnt, int E, int N) {
  int i = blockIdx.x * 256 + threadIdx.x;
  if (i < E) atomicAdd(&cnt[iclamp(dst[i], 0, N - 1)], 1);
}
__global__ void scan_partial(const int* __restrict__ in, int* __restrict__ out,
                             int* __restrict__ bsum, int n) {
  __shared__ int lds[256];
  int t = threadIdx.x;
  int base = blockIdx.x * 1024 + t * 4;
  int v[4];
  int s = 0;
#pragma unroll
  for (int j = 0; j < 4; j++) {
    v[j] = (base + j < n) ? in[base + j] : 0;
    s += v[j];
  }
  lds[t] = s;
  __syncthreads();
  for (int d = 1; d < 256; d <<= 1) {
    int x = 0;
    if (t >= d) x = lds[t - d];
    __syncthreads();
    if (t >= d) lds[t] += x;
    __syncthreads();
  }
  int run = (t > 0) ? lds[t - 1] : 0;
  if (t == 255) bsum[blockIdx.x] = lds[255];
#pragma unroll
  for (int j = 0; j < 4; j++) {
    if (base + j < n) out[base + j] = run;
    run += v[j];
  }
}
// parallel exclusive scan of bsum[0..nb), nb <= 256, one block of 256
__global__ void scan_small2(int* __restrict__ bsum, int nb) {
  __shared__ int lds[256];
  int t = threadIdx.x;
  int v = (t < nb) ? bsum[t] : 0;
  lds[t] = v;
  __syncthreads();
  for (int d = 1; d < 256; d <<= 1) {
    int x = 0;
    if (t >= d) x = lds[t - d];
    __syncthreads();
    if (t >= d) lds[t] += x;
    __syncthreads();
  }
  if (t < nb) bsum[t] = (t > 0) ? lds[t - 1] : 0;
}
__global__ void scan_add(int* out, const int* bsum, int n) {
  int i = blockIdx.x * 256 + threadIdx.x;
  if (i < n) out[i] += bsum[i >> 10];
}
__global__ void fill_k(const int* __restrict__ src, const int* __restrict__ dst,
                       const int* __restrict__ off, int* __restrict__ cur,
                       int* __restrict__ sorted, int E, int N) {
  int i = blockIdx.x * 256 + threadIdx.x;
  if (i < E) {
    int d = iclamp(dst[i], 0, N - 1);
    int p = off[d] + atomicAdd(&cur[d], 1);
    sorted[iclamp(p, 0, E - 1)] = src[i];
  }
}
__global__ void dinv_k(const int* __restrict__ cnt, float* __restrict__ dinv, int n) {
  int i = blockIdx.x * 256 + threadIdx.x;
  if (i < n) dinv[i] = rsqrtf((float)max(cnt[i], 0) + 1.0f);
}

// ---------------- GAT aggregation: one wave per dst, single-pass softmax ----
__global__ void gat_agg(const int* __restrict__ off, const int* __restrict__ cnt,
                        const int* __restrict__ ssrc,
                        const __hip_bfloat16* __restrict__ hs,
                        const float* __restrict__ es, const float* __restrict__ ed,
                        const void* __restrict__ xdst, const void* __restrict__ bias,
                        void* __restrict__ outb, size_t ooff, int nt_out,
                        int N, int Ns, int E, const int* __restrict__ flag) {
  int wid = (blockIdx.x * 256 + threadIdx.x) >> 6;
  if (wid >= N) return;
  int isf32 = *flag;
  int lane = threadIdx.x & 63;
  int hh = lane >> 4;
  int c0 = hh * 32 + (lane & 15) * 2;
  int deg = iclamp(cnt[wid], 0, E);
  int o = iclamp(off[wid], 0, E - deg);
  float edv = ed[wid * 4 + hh];
  float sum = 0.f, a0 = 0.f, a1 = 0.f;
  int e = 0;
  for (; e + 4 <= deg; e += 4) {
    int s0 = iclamp(ssrc[o + e + 0], 0, Ns - 1);
    int s1 = iclamp(ssrc[o + e + 1], 0, Ns - 1);
    int s2 = iclamp(ssrc[o + e + 2], 0, Ns - 1);
    int s3 = iclamp(ssrc[o + e + 3], 0, Ns - 1);
    float e0 = es[s0 * 4 + hh], e1 = es[s1 * 4 + hh];
    float e2 = es[s2 * 4 + hh], e3 = es[s3 * 4 + hh];
    uint32_t u0 = *(const uint32_t*)&hs[(size_t)s0 * 128 + c0];
    uint32_t u1 = *(const uint32_t*)&hs[(size_t)s1 * 128 + c0];
    uint32_t u2 = *(const uint32_t*)&hs[(size_t)s2 * 128 + c0];
    uint32_t u3 = *(const uint32_t*)&hs[(size_t)s3 * 128 + c0];
    float w0 = __expf(lrelu(e0 + edv));
    float w1 = __expf(lrelu(e1 + edv));
    float w2 = __expf(lrelu(e2 + edv));
    float w3 = __expf(lrelu(e3 + edv));
    sum += (w0 + w1) + (w2 + w3);
    float2 f0 = bf2f(u0), f1 = bf2f(u1), f2 = bf2f(u2), f3 = bf2f(u3);
    a0 += w0 * f0.x + w1 * f1.x + w2 * f2.x + w3 * f3.x;
    a1 += w0 * f0.y + w1 * f1.y + w2 * f2.y + w3 * f3.y;
  }
  for (; e < deg; e++) {
    int s = iclamp(ssrc[o + e], 0, Ns - 1);
    float w = __expf(lrelu(es[s * 4 + hh] + edv));
    sum += w;
    float2 f = bf2f(*(const uint32_t*)&hs[(size_t)s * 128 + c0]);
    a0 += w * f.x;
    a1 += w * f.y;
  }
  float inv = 1.f / (sum + 1e-16f);
  float x0, x1, b0, b1;
  if (isf32) {
    const float* xf = (const float*)xdst + (size_t)wid * 128 + c0;
    x0 = xf[0]; x1 = xf[1];
    const float* bf_ = (const float*)bias + c0;
    b0 = bf_[0]; b1 = bf_[1];
  } else {
    float2 xf = bf2f(*(const uint32_t*)&((const __hip_bfloat16*)xdst)[(size_t)wid * 128 + c0]);
    float2 bv = bf2f(*(const uint32_t*)&((const __hip_bfloat16*)bias)[c0]);
    x0 = xf.x; x1 = xf.y; b0 = bv.x; b1 = bv.y;
  }
  float r0 = x0 + 0.5f * (a0 * inv + b0);
  float r1 = x1 + 0.5f * (a1 * inv + b1);
  if (isf32) {
    f32x2* op = (f32x2*)((float*)outb + ooff + (size_t)wid * 128 + c0);
    f32x2 rv = {r0, r1};
    if (nt_out) __builtin_nontemporal_store(rv, op);
    else *op = rv;
  } else {
    *(uint32_t*)&((uint16_t*)outb)[ooff + (size_t)wid * 128 + c0] = f2bf_pack(r0, r1);
  }
}

// ---------------- GCN aggregation: one wave per dst node, 4-way ILP ---------
__global__ void gcn_agg(const int* __restrict__ off, const int* __restrict__ cnt,
                        const int* __restrict__ ssrc,
                        const __hip_bfloat16* __restrict__ xw,
                        const float* __restrict__ dinv,
                        const void* __restrict__ x, const void* __restrict__ bias,
                        void* __restrict__ outb, size_t ooff,
                        int N, int E, const int* __restrict__ flag) {
  int wid = (blockIdx.x * 256 + threadIdx.x) >> 6;
  if (wid >= N) return;
  int isf32 = *flag;
  int lane = threadIdx.x & 63;
  int c0 = lane * 2;
  int deg = iclamp(cnt[wid], 0, E);
  int o = iclamp(off[wid], 0, E - deg);
  float a0 = 0.f, a1 = 0.f;
  int e = 0;
  for (; e + 4 <= deg; e += 4) {
    int s0 = iclamp(ssrc[o + e + 0], 0, N - 1);
    int s1 = iclamp(ssrc[o + e + 1], 0, N - 1);
    int s2 = iclamp(ssrc[o + e + 2], 0, N - 1);
    int s3 = iclamp(ssrc[o + e + 3], 0, N - 1);
    float d0 = dinv[s0], d1 = dinv[s1], d2 = dinv[s2], d3 = dinv[s3];
    uint32_t u0 = *(const uint32_t*)&xw[(size_t)s0 * 128 + c0];
    uint32_t u1 = *(const uint32_t*)&xw[(size_t)s1 * 128 + c0];
    uint32_t u2 = *(const uint32_t*)&xw[(size_t)s2 * 128 + c0];
    uint32_t u3 = *(const uint32_t*)&xw[(size_t)s3 * 128 + c0];
    float2 f0 = bf2f(u0), f1 = bf2f(u1), f2 = bf2f(u2), f3 = bf2f(u3);
    a0 += d0 * f0.x + d1 * f1.x + d2 * f2.x + d3 * f3.x;
    a1 += d0 * f0.y + d1 * f1.y + d2 * f2.y + d3 * f3.y;
  }
  for (; e < deg; e++) {
    int s = iclamp(ssrc[o + e], 0, N - 1);
    float ds = dinv[s];
    float2 f = bf2f(*(const uint32_t*)&xw[(size_t)s * 128 + c0]);
    a0 += ds * f.x;
    a1 += ds * f.y;
  }
  float di = dinv[wid];
  float2 sf = bf2f(*(const uint32_t*)&xw[(size_t)wid * 128 + c0]);
  float agg0 = di * a0 + sf.x * di * di;
  float agg1 = di * a1 + sf.y * di * di;
  float x0, x1, b0, b1;
  if (isf32) {
    f32x2 xf = __builtin_nontemporal_load(
        (const f32x2*)((const float*)x + (size_t)wid * 128 + c0));
    x0 = xf.x; x1 = xf.y;
    const float* bf_ = (const float*)bias + c0;
    b0 = bf_[0]; b1 = bf_[1];
  } else {
    float2 xf = bf2f(*(const uint32_t*)&((const __hip_bfloat16*)x)[(size_t)wid * 128 + c0]);
    float2 bv = bf2f(*(const uint32_t*)&((const __hip_bfloat16*)bias)[c0]);
    x0 = xf.x; x1 = xf.y; b0 = bv.x; b1 = bv.y;
  }
  float r0 = x0 + 0.2f * (agg0 + b0);
  float r1 = x1 + 0.2f * (agg1 + b1);
  if (isf32) {
    f32x2 rv = {r0, r1};
    __builtin_nontemporal_store(rv, (f32x2*)((float*)outb + ooff + (size_t)wid * 128 + c0));
  } else {
    *(uint32_t*)&((uint16_t*)outb)[ooff + (size_t)wid * 128 + c0] = f2bf_pack(r0, r1);
  }
}

extern "C" void kernel_launch(void* const* d_in, const int* in_sizes, int n_in,
                              void* d_out, int out_size, void* d_ws, size_t ws_size,
                              hipStream_t stream) {
  const void* xb = d_in[0];
  const void* xc = d_in[1];
  const void* xt = d_in[2];
  const void* Ws1 = d_in[3];
  const void* Wd1 = d_in[4];
  const void* a_s1 = d_in[5];
  const void* a_d1 = d_in[6];
  const void* b1 = d_in[7];
  const void* Ws2 = d_in[8];
  const void* Wd2 = d_in[9];
  const void* a_s2 = d_in[10];
  const void* a_d2 = d_in[11];
  const void* b2 = d_in[12];
  const void* Wg = d_in[13];
  const void* bg = d_in[14];
  const int* b2c_src = (const int*)d_in[15];
  const int* b2c_dst = (const int*)d_in[16];
  const int* c2t_src = (const int*)d_in[17];
  const int* c2t_dst = (const int*)d_in[18];
  const int* adj_src = (const int*)d_in[19];
  const int* adj_dst = (const int*)d_in[20];

  const int Nb = in_sizes[0] / 128, Nc = in_sizes[1] / 128, Nt = in_sizes[2] / 128;
  const int Ebc = in_sizes[15], Ect = in_sizes[17], Eadj = in_sizes[19];

  auto al = [](size_t x) { return (x + 255) & ~(size_t)255; };
  char* base = (char*)d_ws;

  size_t oFlag = 0;
  size_t oWT = 256;
  size_t oXW = oWT + al(5 * 16384 * 2);
  size_t oPool = oXW + al((size_t)Nb * 256);

  // phase 1 pool
  size_t p1 = oPool;
  size_t o_ed1 = p1; p1 += al((size_t)Nc * 16);
  size_t o_hd1 = p1;
  size_t ov = o_hd1;
  size_t o_es1 = ov; ov += al((size_t)Nb * 16);
  size_t o_cntc = ov; ov += al((size_t)Nc * 4);
  size_t o_offc = ov; ov += al((size_t)Nc * 4);
  size_t o_curc = ov; ov += al((size_t)Nc * 4);
  size_t o_srtbc = ov; ov += al((size_t)Ebc * 4);
  size_t o_bs1 = ov; ov += al(1024);
  size_t slot1 = al((size_t)Nc * 256);
  size_t end1 = o_hd1 + (ov - o_hd1 > slot1 ? ov - o_hd1 : slot1);

  // phase 2 pool
  size_t p2 = oPool;
  size_t o_hs2 = p2; p2 += al((size_t)Nc * 256);
  size_t o_hd2 = p2; p2 += al((size_t)Nt * 256);
  size_t o_es2 = p2; p2 += al((size_t)Nc * 16);
  size_t o_ed2 = p2; p2 += al((size_t)Nt * 16);
  size_t o_cntt = p2; p2 += al((size_t)Nt * 4);
  size_t o_offt = p2; p2 += al((size_t)Nt * 4);
  size_t o_curt = p2; p2 += al((size_t)Nt * 4);
  size_t o_srtct = p2; p2 += al((size_t)Ect * 4);
  size_t o_bs2 = p2; p2 += al(1024);
  size_t end2 = p2;

  // phase 3 pool
  size_t p3 = oPool;
  size_t o_cntb = p3; p3 += al((size_t)Nb * 4);
  size_t o_offb = p3; p3 += al((size_t)Nb * 4);
  size_t o_curb = p3; p3 += al((size_t)Nb * 4);
  size_t o_dinv = p3; p3 += al((size_t)Nb * 4);
  size_t o_srtadj = p3; p3 += al((size_t)Eadj * 4);
  size_t o_bs3 = p3; p3 += al(1024);
  size_t end3 = p3;

  size_t required = end1;
  if (end2 > required) required = end2;
  if (end3 > required) required = end3;
  if (required > ws_size) return;

  int* flag = (int*)(base + oFlag);
  __hip_bfloat16* WT = (__hip_bfloat16*)(base + oWT);
  __hip_bfloat16* XW = (__hip_bfloat16*)(base + oXW);

  const size_t off_b_out = 0;
  const size_t off_c_out = (size_t)Nb * 128;
  const size_t off_t_out = off_c_out + (size_t)Nc * 128;

  detect_k<<<1, 256, 0, stream>>>((const uint32_t*)Ws1, flag);

  transp_k<<<64, 256, 0, stream>>>(Ws1, WT + 0 * 16384, flag);
  transp_k<<<64, 256, 0, stream>>>(Wd1, WT + 1 * 16384, flag);
  transp_k<<<64, 256, 0, stream>>>(Ws2, WT + 2 * 16384, flag);
  transp_k<<<64, 256, 0, stream>>>(Wd2, WT + 3 * 16384, flag);
  transp_k<<<64, 256, 0, stream>>>(Wg, WT + 4 * 16384, flag);

  // ================= Phase 1: GAT building -> cable =================
  {
    __hip_bfloat16* hd1 = (__hip_bfloat16*)(base + o_hd1);
    float* ed1 = (float*)(base + o_ed1);
    mm_xw<<<(Nc + 63) / 64, 256, 0, stream>>>(xc, 0, WT + 1 * 16384, hd1, Nc, flag);
    alpha_dot<<<(Nc * 4 + 255) / 256, 256, 0, stream>>>(hd1, a_d1, ed1, Nc, flag);
    float* es1 = (float*)(base + o_es1);
    int* cnt_c = (int*)(base + o_cntc);
    int* off_c = (int*)(base + o_offc);
    int* cur_c = (int*)(base + o_curc);
    int* srt = (int*)(base + o_srtbc);
    int* bsum = (int*)(base + o_bs1);
    mm_xw<<<(Nb + 63) / 64, 256, 0, stream>>>(xb, 0, WT + 0 * 16384, XW, Nb, flag);
    alpha_dot<<<(Nb * 4 + 255) / 256, 256, 0, stream>>>(XW, a_s1, es1, Nb, flag);
    zero2_i32<<<(Nc + 255) / 256, 256, 0, stream>>>(cnt_c, cur_c, Nc);
    hist_k<<<(Ebc + 255) / 256, 256, 0, stream>>>(b2c_dst, cnt_c, Ebc, Nc);
    int nblk = (Nc + 1023) / 1024;
    scan_partial<<<nblk, 256, 0, stream>>>(cnt_c, off_c, bsum, Nc);
    scan_small2<<<1, 256, 0, stream>>>(bsum, nblk);
    scan_add<<<(Nc + 255) / 256, 256, 0, stream>>>(off_c, bsum, Nc);
    fill_k<<<(Ebc + 255) / 256, 256, 0, stream>>>(b2c_src, b2c_dst, off_c, cur_c, srt, Ebc, Nc);
    gat_agg<<<(int)(((size_t)Nc * 64 + 255) / 256), 256, 0, stream>>>(
        off_c, cnt_c, srt, XW, es1, ed1, xc, b1, d_out, off_c_out, 0, Nc, Nb, Ebc, flag);
  }

  // ================= Phase 2: GAT cable(updated) -> transformer =================
  {
    __hip_bfloat16* hs2 = (__hip_bfloat16*)(base + o_hs2);
    __hip_bfloat16* hd2 = (__hip_bfloat16*)(base + o_hd2);
    float* es2 = (float*)(base + o_es2);
    float* ed2 = (float*)(base + o_ed2);
    int* cnt_t = (int*)(base + o_cntt);
    int* off_t = (int*)(base + o_offt);
    int* cur_t = (int*)(base + o_curt);
    int* srt = (int*)(base + o_srtct);
    int* bsum = (int*)(base + o_bs2);
    mm_xw<<<(Nc + 63) / 64, 256, 0, stream>>>(d_out, off_c_out, WT + 2 * 16384, hs2, Nc, flag);
    mm_xw<<<(Nt + 63) / 64, 256, 0, stream>>>(xt, 0, WT + 3 * 16384, hd2, Nt, flag);
    alpha_dot<<<(Nc * 4 + 255) / 256, 256, 0, stream>>>(hs2, a_s2, es2, Nc, flag);
    alpha_dot<<<(Nt * 4 + 255) / 256, 256, 0, stream>>>(hd2, a_d2, ed2, Nt, flag);
    zero2_i32<<<(Nt + 255) / 256, 256, 0, stream>>>(cnt_t, cur_t, Nt);
    hist_k<<<(Ect + 255) / 256, 256, 0, stream>>>(c2t_dst, cnt_t, Ect, Nt);
    int nblk = (Nt + 1023) / 1024;
    scan_partial<<<nblk, 256, 0, stream>>>(cnt_t, off_t, bsum, Nt);
    scan_small2<<<1, 256, 0, stream>>>(bsum, nblk);
    scan_add<<<(Nt + 255) / 256, 256, 0, stream>>>(off_t, bsum, Nt);
    fill_k<<<(Ect + 255) / 256, 256, 0, stream>>>(c2t_src, c2t_dst, off_t, cur_t, srt, Ect, Nt);
    gat_agg<<<(int)(((size_t)Nt * 64 + 255) / 256), 256, 0, stream>>>(
        off_t, cnt_t, srt, hs2, es2, ed2, xt, b2, d_out, off_t_out, 1, Nt, Nc, Ect, flag);
  }

  // ================= Phase 3: GCN building adjacency =================
  {
    int* cnt_b = (int*)(base + o_cntb);
    int* off_b = (int*)(base + o_offb);
    int* cur_b = (int*)(base + o_curb);
    float* dinv = (float*)(base + o_dinv);
    int* srt = (int*)(base + o_srtadj);
    int* bsum = (int*)(base + o_bs3);
    mm_xw<<<(Nb + 63) / 64, 256, 0, stream>>>(xb, 0, WT + 4 * 16384, XW, Nb, flag);
    zero2_i32<<<(Nb + 255) / 256, 256, 0, stream>>>(cnt_b, cur_b, Nb);
    hist_k<<<(Eadj + 255) / 256, 256, 0, stream>>>(adj_dst, cnt_b, Eadj, Nb);
    int nblk = (Nb + 1023) / 1024;
    scan_partial<<<nblk, 256, 0, stream>>>(cnt_b, off_b, bsum, Nb);
    scan_small2<<<1, 256, 0, stream>>>(bsum, nblk);
    scan_add<<<(Nb + 255) / 256, 256, 0, stream>>>(off_b, bsum, Nb);
    dinv_k<<<(Nb + 255) / 256, 256, 0, stream>>>(cnt_b, dinv, Nb);
    fill_k<<<(Eadj + 255) / 256, 256, 0, stream>>>(adj_src, adj_dst, off_b, cur_b, srt, Eadj, Nb);
    gcn_agg<<<(int)(((size_t)Nb * 64 + 255) / 256), 256, 0, stream>>>(
        off_b, cnt_b, srt, XW, dinv, xb, bg, d_out, off_b_out, Nb, Eadj, flag);
  }
}